// Round 7
// baseline (216.456 us; speedup 1.0000x reference)
//
#include <hip/hip_runtime.h>
#include <math.h>

// DynamicHybridRouter via bf16-split MFMA (3-term: xh*wh + xh*wl + xl*wh).
// R7: R3-R6 all plateaued 65-80us regardless of structure, pipes <10% busy, time
// insensitive to HBM traffic (R5 replays: x L3-resident, still 78us). Common factor:
// x A-frag loads were 16-segment gathers with 8KB stride (same-L2-channel hotspot,
// ~16 serialized transactions per instruction). Fix: stage x through private LDS
// with global_load_lds width=16 (each instr = 2 contiguous 512B row spans, fully
// coalesced), double-buffered per wave, zero K-loop barriers. B per-step from L2
// with one-step register prefetch (R4-style). DMA->ds_read ordering: in-order vmcnt
// retirement + explicit s_waitcnt vmcnt(16) per chunk (B-step waits drain older DMAs).

#define NROWS 16384
#define DIM   2048
#define NEXP  64
#define BM    16
#define TPB   256
#define KSLICE 512
#define KSTEPS 16              // MFMA K-steps per wave (K=32 each)
#define CH    4                // steps per staged chunk (k-span 128)
#define NCH   (KSTEPS / CH)    // 4 chunks

typedef __attribute__((ext_vector_type(4))) float f32x4;
typedef __attribute__((ext_vector_type(8))) short bf16x8;

__device__ inline void dma16(const void* g, void* l) {
  __builtin_amdgcn_global_load_lds(
      (const __attribute__((address_space(1))) unsigned int*)g,
      (__attribute__((address_space(3))) unsigned int*)l, 16, 0, 0);
}

// ---- prologue: w [64][2048] f32 -> B-frag-ordered bf16 hi/lo in ws ----
// frag slot = (kstep*4 + t): 64 lanes x bf16x8; lane's frag:
// w[e=16t+(lane&15)][k = kstep*32 + (lane>>4)*8 + j], j=0..7.
__global__ void wfrag_kernel(const float* __restrict__ gw,
                             unsigned short* __restrict__ wsH,
                             unsigned short* __restrict__ wsL) {
  int slot  = blockIdx.x * 256 + threadIdx.x;   // 0..16383
  int lane  = slot & 63;
  int t     = (slot >> 6) & 3;
  int kstep = slot >> 8;
  int e  = 16 * t + (lane & 15);
  int k0 = kstep * 32 + (lane >> 4) * 8;
  const float* src = gw + (size_t)e * DIM + k0;
  bf16x8 vh, vl;
#pragma unroll
  for (int j = 0; j < 8; ++j) {
    float w = src[j];
    unsigned u = __float_as_uint(w);
    vh[j] = (short)(u >> 16);
    float hi = __uint_as_float(u & 0xffff0000u);
    float rl = w - hi;
    vl[j] = (short)(__float_as_uint(rl) >> 16);
  }
  ((bf16x8*)wsH)[slot] = vh;
  ((bf16x8*)wsL)[slot] = vl;
}

// ---- main kernel ----
__global__ __launch_bounds__(TPB, 2)
void router_mfma(const float* __restrict__ x,
                 const unsigned short* __restrict__ wsH,
                 const unsigned short* __restrict__ wsL,
                 const float* __restrict__ gb,
                 const int* __restrict__ mat,
                 float* __restrict__ out) {
  // per-wave x staging: 2 bufs x (16 rows x 128 floats) = 4096 floats/wave; 64KB total.
  // Reused post-loop as 4 partial-logit slabs (16KB).
  __shared__ __align__(16) float xstage[4 * 2 * BM * CH * 32];
  __shared__ float p_a[BM], p_b[BM];
  __shared__ int   p_i[BM], p_j[BM];
  __shared__ int   s_flag;

  const int tid  = threadIdx.x;
  const int ksl  = tid >> 6;     // wave = K-slice 0..3
  const int lane = tid & 63;
  const int m    = lane & 15;
  const int kg   = lane >> 4;
  const int row0 = blockIdx.x * BM;

  if (tid < 64) {
    unsigned long long b = __ballot(mat[lane] == 0);
    if (lane == 0) s_flag = (b != 0ull) ? 1 : 0;
  }

  f32x4 acc[4];
#pragma unroll
  for (int t = 0; t < 4; ++t) acc[t] = (f32x4)0.0f;

  const bf16x8* wsHf = (const bf16x8*)wsH;
  const bf16x8* wsLf = (const bf16x8*)wsL;
  const int gs0 = ksl * KSTEPS;  // this wave's first global K-step

  // staging source: instr i covers rows 2i,2i+1 of this block's 16 rows;
  // lane -> row 2i+(lane>>5), bytes (lane&31)*16 within the 512B chunk-row span.
  const float* xg = x + (size_t)(row0 + (lane >> 5)) * DIM + ksl * KSLICE + (lane & 31) * 4;
  float* xbuf = xstage + ksl * (2 * BM * CH * 32);   // wave-private, 4096 floats

  // DMA chunk 0 -> buf 0, then drain (once per kernel)
#pragma unroll
  for (int i = 0; i < 8; ++i)
    dma16(xg + (size_t)(2 * i) * DIM, xbuf + i * 256);
  asm volatile("s_waitcnt vmcnt(0)" ::: "memory");

  // prefetch B for step 0
  bf16x8 bh[4], bl[4];
#pragma unroll
  for (int t = 0; t < 4; ++t) {
    bh[t] = wsHf[(size_t)((gs0 + 0) * 4 + t) * 64 + lane];
    bl[t] = wsLf[(size_t)((gs0 + 0) * 4 + t) * 64 + lane];
  }

#pragma unroll 1
  for (int c = 0; c < NCH; ++c) {
    // DMA next chunk into the other buffer (8 instr, fully coalesced)
    if (c + 1 < NCH) {
      float* dst = xbuf + ((c + 1) & 1) * 2048;
      const float* src = xg + (c + 1) * (CH * 32);
#pragma unroll
      for (int i = 0; i < 8; ++i)
        dma16(src + (size_t)(2 * i) * DIM, dst + i * 256);
    }
    // ensure DMA(c) retired: <=16 youngest outstanding = B(st0) 8 + DMA(c+1) 8
    asm volatile("s_waitcnt vmcnt(16)" ::: "memory");
    const float* xc = xbuf + (c & 1) * 2048;   // rows row-major, stride 128 floats

#pragma unroll
    for (int st = 0; st < CH; ++st) {
      const int gs  = c * CH + st;
      const int gsn = (gs + 1 < KSTEPS) ? (gs + 1) : gs;
      // prefetch B for next step (consumed next iteration)
      bf16x8 bhn[4], bln[4];
#pragma unroll
      for (int t = 0; t < 4; ++t) {
        bhn[t] = wsHf[(size_t)((gs0 + gsn) * 4 + t) * 64 + lane];
        bln[t] = wsLf[(size_t)((gs0 + gsn) * 4 + t) * 64 + lane];
      }
      // A-frag: 8 fp32 from LDS (2x ds_read_b128), convert to bf16 hi/lo
      const float* xr = xc + m * 128 + st * 32 + kg * 8;
      float4 v0 = *(const float4*)xr;
      float4 v1 = *(const float4*)(xr + 4);
      bf16x8 ah, al;
      {
        float ff[8] = {v0.x, v0.y, v0.z, v0.w, v1.x, v1.y, v1.z, v1.w};
#pragma unroll
        for (int j = 0; j < 8; ++j) {
          unsigned u = __float_as_uint(ff[j]);
          ah[j] = (short)(u >> 16);
          float hi = __uint_as_float(u & 0xffff0000u);
          float rl = ff[j] - hi;
          al[j] = (short)(__float_as_uint(rl) >> 16);
        }
      }
      // 3-term MFMA over 4 expert tiles
#pragma unroll
      for (int t = 0; t < 4; ++t) {
        acc[t] = __builtin_amdgcn_mfma_f32_16x16x32_bf16(ah, bh[t], acc[t], 0, 0, 0);
        acc[t] = __builtin_amdgcn_mfma_f32_16x16x32_bf16(ah, bl[t], acc[t], 0, 0, 0);
        acc[t] = __builtin_amdgcn_mfma_f32_16x16x32_bf16(al, bh[t], acc[t], 0, 0, 0);
      }
#pragma unroll
      for (int t = 0; t < 4; ++t) { bh[t] = bhn[t]; bl[t] = bln[t]; }
    }
  }

  // ---- epilogue: reuse xstage as 4 partial slabs (all waves past K-loop) ----
  __syncthreads();
  float* slab = xstage;
  {
    float* sl = slab + ksl * (BM * NEXP);
#pragma unroll
    for (int t = 0; t < 4; ++t)
#pragma unroll
      for (int reg = 0; reg < 4; ++reg)
        sl[(kg * 4 + reg) * NEXP + 16 * t + m] = acc[t][reg];
  }
  __syncthreads();

  // 4 K-slice slabs + bias -> logits in slab[0..1024)
  for (int idx = tid; idx < BM * NEXP; idx += TPB) {
    float v = slab[idx] + slab[1024 + idx] + slab[2048 + idx] + slab[3072 + idx]
            + gb[idx & (NEXP - 1)];
    slab[idx] = v;
  }
  __syncthreads();

  const int flag = s_flag;

  // per-row routing (threads 0..15; rotated scan spreads LDS banks)
  if (tid < BM) {
    const float* rowp = slab + tid * NEXP;
    if (flag == 0) {
      float m1 = -1e30f, m2 = -1e30f;
      int i1 = 0, i2 = 0;
      for (int ee = 0; ee < NEXP; ++ee) {
        int e = (ee + tid) & (NEXP - 1);
        float v = rowp[e];
        if (v > m1) { m2 = m1; i2 = i1; m1 = v; i1 = e; }
        else if (v > m2) { m2 = v; i2 = e; }
      }
      float t = expf(m2 - m1);
      float pa = 1.0f / (1.0f + t);
      p_a[tid] = pa;
      p_b[tid] = t * pa;
      p_i[tid] = i1;
      p_j[tid] = i2;
    } else {
      float mx = -1e30f;
      for (int ee = 0; ee < NEXP; ++ee)
        mx = fmaxf(mx, rowp[(ee + tid) & (NEXP - 1)]);
      float ssum = 0.0f;
      for (int ee = 0; ee < NEXP; ++ee)
        ssum += expf((rowp[(ee + tid) & (NEXP - 1)] - mx) * 0.5f);  // /T=2
      p_a[tid] = mx;
      p_b[tid] = 1.0f / ssum;
    }
  }
  __syncthreads();

  // output: 16x64 tile = 256 float4, one per thread
  {
    int q  = tid;
    int r  = q >> 4;
    int e0 = (q & 15) * 4;
    float4 v;
    if (flag == 0) {
      int i1 = p_i[r], i2 = p_j[r];
      float a = p_a[r], b = p_b[r];
      v.x = (e0 + 0 == i1) ? a : (e0 + 0 == i2) ? b : 0.0f;
      v.y = (e0 + 1 == i1) ? a : (e0 + 1 == i2) ? b : 0.0f;
      v.z = (e0 + 2 == i1) ? a : (e0 + 2 == i2) ? b : 0.0f;
      v.w = (e0 + 3 == i1) ? a : (e0 + 3 == i2) ? b : 0.0f;
    } else {
      float mx = p_a[r], inv = p_b[r];
      const float* rowp = slab + r * NEXP + e0;
      v.x = expf((rowp[0] - mx) * 0.5f) * inv;
      v.y = expf((rowp[1] - mx) * 0.5f) * inv;
      v.z = expf((rowp[2] - mx) * 0.5f) * inv;
      v.w = expf((rowp[3] - mx) * 0.5f) * inv;
    }
    *(float4*)(out + (size_t)(row0 + r) * NEXP + e0) = v;
  }
}

extern "C" void kernel_launch(void* const* d_in, const int* in_sizes, int n_in,
                              void* d_out, int out_size, void* d_ws, size_t ws_size,
                              hipStream_t stream) {
  const float* x  = (const float*)d_in[0];
  const float* gw = (const float*)d_in[1];
  const float* gb = (const float*)d_in[2];
  const int*   mt = (const int*)d_in[3];
  float* outp = (float*)d_out;
  (void)in_sizes; (void)n_in; (void)out_size; (void)ws_size;

  unsigned short* wsH = (unsigned short*)d_ws;
  unsigned short* wsL = wsH + 64 * DIM;

  wfrag_kernel<<<64, 256, 0, stream>>>(gw, wsH, wsL);
  router_mfma<<<NROWS / BM, TPB, 0, stream>>>(x, wsH, wsL, gb, mt, outp);
}